// Round 6
// baseline (223.607 us; speedup 1.0000x reference)
//
#include <hip/hip_runtime.h>

// ClauseInferModule: C=16, B=64, G=2048, S=8, L=4, 3 steps.
// w-units: w = v*(1000/ln2) => exp((a-b)/gamma)==exp2(wa-wb), gamma*ln==log2 EXACT.
//
// k_step (fused clause+merge), grid=256 blocks x 1024 threads, block=(c,bchunk,ghalf):
//   - stage 4 rows b-interleaved in LDS (lds4[g] = b-quad at atom g, scaled),
//     one ds_read_b128 gathers a literal for 4 b's; softand/softor component-wise.
//   - q stays in REGISTERS (no global q traffic at all).
//   - per-clause max m2 via device-scope atomicMax; 16-block arrival counter +
//     spin (co-residency GUARANTEED: 256 blocks, each <= 1/4 CU, 256 CUs).
//   - merge phase: s3 = softor2(own staged src, own q/max(m2,1)) from registers,
//     writes w-units R, accumulates global m3.
//   softand renorm provably no-op (R<=1 invariant => softand<1 strictly).
//   m3-renorm of step k folds into step k+1 staging scale / final k_scale.
// k_scale: in-place out *= RKF/max(m3,1)  (w -> real).
// where(m>1,s/m,s) == s/max(m,1) exactly.

namespace {
constexpr int C = 16, B = 64, G = 2048, S = 8, L = 4;
constexpr int STEPS = 3;
constexpr int N  = C * B * G;
constexpr float KF  = 1442.6950408889634f;    // 1000/ln2 : real -> w
constexpr float RKF = 6.9314718055994531e-4f; // ln2/1000 : w -> real
}

__device__ __forceinline__ unsigned f2key(float f) {
    unsigned b = __float_as_uint(f);
    return (b & 0x80000000u) ? ~b : (b | 0x80000000u);
}
__device__ __forceinline__ float key2f(unsigned k) {
    return (k & 0x80000000u) ? __uint_as_float(k & 0x7fffffffu)
                             : __uint_as_float(~k);
}
__device__ __forceinline__ float4 f4min(float4 a, float4 b) {
    return make_float4(fminf(a.x,b.x), fminf(a.y,b.y), fminf(a.z,b.z), fminf(a.w,b.w));
}
__device__ __forceinline__ float4 f4max(float4 a, float4 b) {
    return make_float4(fmaxf(a.x,b.x), fmaxf(a.y,b.y), fmaxf(a.z,b.z), fmaxf(a.w,b.w));
}

// mk layout (uints): [0..47] m2[step][c] | [48..50] m3[step] | [64..111] arr[step][c]

__global__ __launch_bounds__(1024, 4) void k_step(const float* __restrict__ src, int step0,
                                                  const int* __restrict__ I,
                                                  float* __restrict__ R,
                                                  unsigned* __restrict__ m2k,
                                                  const unsigned* __restrict__ m3prev,
                                                  unsigned* __restrict__ m3out,
                                                  unsigned* __restrict__ arr) {
    __shared__ float4 lds4[G];        // 32 KB: 4 rows b-interleaved, w-units scaled
    __shared__ float wred[16];
    __shared__ float sh_qden;

    const int blk = blockIdx.x, tid = threadIdx.x;
    const int c = blk >> 4, bchunk = (blk >> 1) & 7, ghalf = blk & 1;
    const int g = ghalf * 1024 + tid, b0 = bchunk * 8;

    // register-cache this thread's 32 indices (b-independent)
    const int4* Ib = (const int4*)(I + (size_t)(c * G + g) * (S * L));
    int4 ix[S];
#pragma unroll
    for (int s = 0; s < S; ++s) ix[s] = Ib[s];

    const float ss = step0 ? KF : 1.0f / fmaxf(key2f(*m3prev) * RKF, 1.0f);
    const int rbase = step0 ? b0 : (c * B + b0);

    // preload group-0 rows: 4 rows, one float2 column per thread (col = tid)
    float2 pa[4];
#pragma unroll
    for (int j = 0; j < 4; ++j)
        pa[j] = ((const float2*)(src + (size_t)(rbase + j) * G))[tid];

    float4 qv[2], sq[2];
    float lmax = -3.0e38f;

#pragma unroll
    for (int grp = 0; grp < 2; ++grp) {
        if (grp) __syncthreads();          // group-0 gathers done before overwrite
        // transpose-stage: lds4[2t], lds4[2t+1] = b-quads for atoms 2t, 2t+1
        lds4[2 * tid]     = make_float4(pa[0].x * ss, pa[1].x * ss, pa[2].x * ss, pa[3].x * ss);
        lds4[2 * tid + 1] = make_float4(pa[0].y * ss, pa[1].y * ss, pa[2].y * ss, pa[3].y * ss);
        if (grp == 0) {                    // prefetch group-1 rows; fly during compute
#pragma unroll
            for (int j = 0; j < 4; ++j)
                pa[j] = ((const float2*)(src + (size_t)(rbase + 4 + j) * G))[tid];
        }
        __syncthreads();                   // staging visible

        sq[grp] = lds4[g];                 // own src b-quad for merge phase

        // softand over L + ONLINE softor over S (component-wise on the b-quad)
        float4 pm = make_float4(-3.0e38f, -3.0e38f, -3.0e38f, -3.0e38f);
        float4 ssum = make_float4(0.f, 0.f, 0.f, 0.f);
#pragma unroll
        for (int s = 0; s < S; ++s) {
            int4 iv = ix[s];
            float4 w0 = lds4[iv.x], w1 = lds4[iv.y], w2 = lds4[iv.z], w3 = lds4[iv.w];
            float4 wm = f4min(f4min(w0, w1), f4min(w2, w3));
            float4 sum = make_float4(
                exp2f(wm.x-w0.x) + exp2f(wm.x-w1.x) + exp2f(wm.x-w2.x) + exp2f(wm.x-w3.x),
                exp2f(wm.y-w0.y) + exp2f(wm.y-w1.y) + exp2f(wm.y-w2.y) + exp2f(wm.y-w3.y),
                exp2f(wm.z-w0.z) + exp2f(wm.z-w1.z) + exp2f(wm.z-w2.z) + exp2f(wm.z-w3.z),
                exp2f(wm.w-w0.w) + exp2f(wm.w-w1.w) + exp2f(wm.w-w2.w) + exp2f(wm.w-w3.w));
            float4 P = make_float4(wm.x - log2f(sum.x), wm.y - log2f(sum.y),
                                   wm.z - log2f(sum.z), wm.w - log2f(sum.w));
            // online logsumexp update (w-units): exact same math as two-pass
            float4 npm = f4max(pm, P);
            ssum.x = ssum.x * exp2f(pm.x - npm.x) + exp2f(P.x - npm.x);
            ssum.y = ssum.y * exp2f(pm.y - npm.y) + exp2f(P.y - npm.y);
            ssum.z = ssum.z * exp2f(pm.z - npm.z) + exp2f(P.z - npm.z);
            ssum.w = ssum.w * exp2f(pm.w - npm.w) + exp2f(P.w - npm.w);
            pm = npm;
        }
        float4 qq = make_float4(pm.x + log2f(ssum.x), pm.y + log2f(ssum.y),
                                pm.z + log2f(ssum.z), pm.w + log2f(ssum.w));
        qv[grp] = qq;
        lmax = fmaxf(lmax, fmaxf(fmaxf(qq.x, qq.y), fmaxf(qq.z, qq.w)));
    }

    // ---- m2: block reduce -> device atomic -> 16-block arrival spin ----
    {
        float m = lmax;
        for (int off = 32; off; off >>= 1) m = fmaxf(m, __shfl_down(m, off));
        if ((tid & 63) == 0) wred[tid >> 6] = m;
        __syncthreads();
        if (tid == 0) {
            float mm = wred[0];
#pragma unroll
            for (int i = 1; i < 16; ++i) mm = fmaxf(mm, wred[i]);
            atomicMax(m2k + c, f2key(mm));
            __threadfence();                           // m2 RMW performed before arrival
            atomicAdd(arr + c, 1u);
            while (__hip_atomic_load(arr + c, __ATOMIC_ACQUIRE,
                                     __HIP_MEMORY_SCOPE_AGENT) < 16u)
                __builtin_amdgcn_s_sleep(1);
            unsigned k2 = __hip_atomic_load(m2k + c, __ATOMIC_ACQUIRE,
                                            __HIP_MEMORY_SCOPE_AGENT);
            sh_qden = 1.0f / fmaxf(key2f(k2) * RKF, 1.0f);
        }
        __syncthreads();
    }
    const float qden = sh_qden;

    // ---- merge phase: all operands in registers ----
    float lm3 = -3.0e38f;
#pragma unroll
    for (int grp = 0; grp < 2; ++grp) {
        float rv[4] = {sq[grp].x, sq[grp].y, sq[grp].z, sq[grp].w};
        float qa[4] = {qv[grp].x, qv[grp].y, qv[grp].z, qv[grp].w};
#pragma unroll
        for (int i = 0; i < 4; ++i) {
            float qx = qa[i] * qden;
            float hi = fmaxf(rv[i], qx), lo = fminf(rv[i], qx);
            float sv = hi + log2f(1.0f + exp2f(lo - hi));   // softor2 (w-units)
            R[(size_t)(c * B + b0 + grp * 4 + i) * G + g] = sv;
            lm3 = fmaxf(lm3, sv);
        }
    }
    // ---- m3: block reduce -> one device atomic per block ----
    for (int off = 32; off; off >>= 1) lm3 = fmaxf(lm3, __shfl_down(lm3, off));
    __syncthreads();                       // wred reuse guard
    if ((tid & 63) == 0) wred[tid >> 6] = lm3;
    __syncthreads();
    if (tid == 0) {
        float mm = wred[0];
#pragma unroll
        for (int i = 1; i < 16; ++i) mm = fmaxf(mm, wred[i]);
        atomicMax(m3out, f2key(mm));
    }
}

// in-place: out(w-units) -> real, scaled by final m3 renorm.
__global__ __launch_bounds__(256) void k_scale(float* __restrict__ R,
                                               const unsigned* __restrict__ m3k) {
    float fs = RKF / fmaxf(key2f(*m3k) * RKF, 1.0f);
    int idx = blockIdx.x * 256 + threadIdx.x;
    float4 r = ((float4*)R)[idx];
    r.x *= fs; r.y *= fs; r.z *= fs; r.w *= fs;
    ((float4*)R)[idx] = r;
}

extern "C" void kernel_launch(void* const* d_in, const int* in_sizes, int n_in,
                              void* d_out, int out_size, void* d_ws, size_t ws_size,
                              hipStream_t stream) {
    const float* x = (const float*)d_in[0];   // (B, G) fp32
    const int*   I = (const int*)d_in[1];     // (C, G, S, L) int32
    float* out = (float*)d_out;               // (C, B, G) fp32 (w-units until k_scale)

    unsigned* mk = (unsigned*)d_ws;           // 128 uints

    hipMemsetAsync(mk, 0, 128 * sizeof(unsigned), stream);

    for (int step = 0; step < STEPS; ++step) {
        int step0 = (step == 0);
        const float* src = step0 ? x : out;
        unsigned* m2k = mk + step * C;
        unsigned* m3out = mk + 48 + step;
        const unsigned* m3prev = mk + 48 + (step ? step - 1 : 0);  // valid ptr; unused if step0
        unsigned* arr = mk + 64 + step * C;
        k_step<<<256, 1024, 0, stream>>>(src, step0, I, out, m2k, m3prev, m3out, arr);
    }
    k_scale<<<N / 4 / 256, 256, 0, stream>>>(out, mk + 48 + STEPS - 1);
}

// Round 7
// 184.505 us; speedup vs baseline: 1.2119x; 1.2119x over previous
//
#include <hip/hip_runtime.h>

// ClauseInferModule: C=16, B=64, G=2048, S=8, L=4, 3 steps.
// w-units: w = v*(1000/ln2) => exp((a-b)/gamma)==exp2(wa-wb), gamma*ln==log2 EXACT.
// Transcendentals are NATIVE v_exp_f32 / v_log_f32 via __builtin_amdgcn_* —
// libm exp2f/log2f lower to multi-instr OCML polys and were the round-4..6
// VALU bottleneck (VALUBusy 48% at 3 waves/SIMD).
// k_clause: block=(c, gtile 256, bchunk 8). I register-cached (32 idx/thread,
//   b-independent). Rows staged 4-at-a-time INTERLEAVED in LDS:
//   lds4[g] = float4(row0..row3)[g] * ss  (32 KB) -> one ds_read_b128 gathers a
//   literal for 4 b's; softand/softor component-wise on the b-quad.
//   Emits q (w-units) + per-clause max m2. softand renorm provably no-op (R<=1).
// k_merge: s3 = softor2(src*ss, q/max(m2,1)); w-units R to d_out; global m3.
//   m3-renorm of step k folds into step k+1 staging scale (and final k_scale).
// k_scale: in-place out *= RKF/max(m3,1)  (w -> real).
// where(m>1,s/m,s) == s/max(m,1) exactly.

namespace {
constexpr int C = 16, B = 64, G = 2048, S = 8, L = 4;
constexpr int STEPS = 3;
constexpr int N  = C * B * G;
constexpr int BG = B * G;
constexpr float KF  = 1442.6950408889634f;    // 1000/ln2 : real -> w
constexpr float RKF = 6.9314718055994531e-4f; // ln2/1000 : w -> real
}

__device__ __forceinline__ float ex2(float x) { return __builtin_amdgcn_exp2f(x); }  // v_exp_f32
__device__ __forceinline__ float lg2(float x) { return __builtin_amdgcn_logf(x); }   // v_log_f32

__device__ __forceinline__ unsigned f2key(float f) {
    unsigned b = __float_as_uint(f);
    return (b & 0x80000000u) ? ~b : (b | 0x80000000u);
}
__device__ __forceinline__ float key2f(unsigned k) {
    return (k & 0x80000000u) ? __uint_as_float(k & 0x7fffffffu)
                             : __uint_as_float(~k);
}

__device__ __forceinline__ float4 f4min(float4 a, float4 b) {
    return make_float4(fminf(a.x,b.x), fminf(a.y,b.y), fminf(a.z,b.z), fminf(a.w,b.w));
}
__device__ __forceinline__ float4 f4max(float4 a, float4 b) {
    return make_float4(fmaxf(a.x,b.x), fmaxf(a.y,b.y), fmaxf(a.z,b.z), fmaxf(a.w,b.w));
}
__device__ __forceinline__ float4 f4exp2sub(float4 m, float4 v) {   // exp2(m - v), native
    return make_float4(ex2(m.x-v.x), ex2(m.y-v.y), ex2(m.z-v.z), ex2(m.w-v.w));
}
__device__ __forceinline__ float4 f4add(float4 a, float4 b) {
    return make_float4(a.x+b.x, a.y+b.y, a.z+b.z, a.w+b.w);
}

// mk layout: [0..47] m2 (C per step), [48..50] m3 per step. memset-0 = identity.

// grid = C*8*8 = 1024 blocks, 256 threads, 4 blocks/CU (32 KB LDS each).
__global__ __launch_bounds__(256, 4) void k_clause(const float* __restrict__ src, int step0,
                                                   const int* __restrict__ I,
                                                   float* __restrict__ q,
                                                   unsigned* __restrict__ m2k,
                                                   const unsigned* __restrict__ m3prev) {
    __shared__ float4 lds4[G];      // 32 KB: 4 rows interleaved, scaled to w-units
    __shared__ float wmax[4];

    const int blk = blockIdx.x, tid = threadIdx.x;
    const int bchunk = blk & 7, gtile = (blk >> 3) & 7, c = blk >> 6;
    const int g = gtile * 256 + tid, b0 = bchunk * 8;

    // register-cache this thread's 32 indices (b-independent, reused for all 8 b's)
    const int4* Ib = (const int4*)(I + (size_t)(c * G + g) * (S * L));
    int4 ix[S];
#pragma unroll
    for (int s = 0; s < S; ++s) ix[s] = Ib[s];

    const float ss = step0 ? KF : 1.0f / fmaxf(key2f(*m3prev) * RKF, 1.0f);
    const int rbase = step0 ? b0 : (c * B + b0);

    float lmax = -3.0e38f;

    // preload group-0 rows (4 rows x 2 float4-columns per thread)
    float4 ca[4], cb[4];
#pragma unroll
    for (int j = 0; j < 4; ++j) {
        const float4* rp = (const float4*)(src + (size_t)(rbase + j) * G);
        ca[j] = rp[tid]; cb[j] = rp[tid + 256];
    }

#pragma unroll
    for (int grp = 0; grp < 2; ++grp) {
        __syncthreads();            // prior group's gathers done
        // transpose-stage: lds4[g'] = (row0,row1,row2,row3)[g'] * ss
        {
            int col0 = 4 * tid, col1 = 4 * (tid + 256);
            float4 t;
            t = make_float4(ca[0].x, ca[1].x, ca[2].x, ca[3].x);
            t.x*=ss; t.y*=ss; t.z*=ss; t.w*=ss; lds4[col0 + 0] = t;
            t = make_float4(ca[0].y, ca[1].y, ca[2].y, ca[3].y);
            t.x*=ss; t.y*=ss; t.z*=ss; t.w*=ss; lds4[col0 + 1] = t;
            t = make_float4(ca[0].z, ca[1].z, ca[2].z, ca[3].z);
            t.x*=ss; t.y*=ss; t.z*=ss; t.w*=ss; lds4[col0 + 2] = t;
            t = make_float4(ca[0].w, ca[1].w, ca[2].w, ca[3].w);
            t.x*=ss; t.y*=ss; t.z*=ss; t.w*=ss; lds4[col0 + 3] = t;
            t = make_float4(cb[0].x, cb[1].x, cb[2].x, cb[3].x);
            t.x*=ss; t.y*=ss; t.z*=ss; t.w*=ss; lds4[col1 + 0] = t;
            t = make_float4(cb[0].y, cb[1].y, cb[2].y, cb[3].y);
            t.x*=ss; t.y*=ss; t.z*=ss; t.w*=ss; lds4[col1 + 1] = t;
            t = make_float4(cb[0].z, cb[1].z, cb[2].z, cb[3].z);
            t.x*=ss; t.y*=ss; t.z*=ss; t.w*=ss; lds4[col1 + 2] = t;
            t = make_float4(cb[0].w, cb[1].w, cb[2].w, cb[3].w);
            t.x*=ss; t.y*=ss; t.z*=ss; t.w*=ss; lds4[col1 + 3] = t;
        }
        if (grp == 0) {             // issue group-1 loads; they fly during compute
#pragma unroll
            for (int j = 0; j < 4; ++j) {
                const float4* rp = (const float4*)(src + (size_t)(rbase + 4 + j) * G);
                ca[j] = rp[tid]; cb[j] = rp[tid + 256];
            }
        }
        __syncthreads();            // staging visible

        // gather + softand over L (component-wise on the b-quad)
        float4 P[S];
#pragma unroll
        for (int s = 0; s < S; ++s) {
            int4 iv = ix[s];
            float4 w0 = lds4[iv.x], w1 = lds4[iv.y], w2 = lds4[iv.z], w3 = lds4[iv.w];
            float4 wm = f4min(f4min(w0, w1), f4min(w2, w3));
            float4 sum = f4add(f4add(f4exp2sub(wm, w0), f4exp2sub(wm, w1)),
                               f4add(f4exp2sub(wm, w2), f4exp2sub(wm, w3)));
            P[s] = make_float4(wm.x - lg2(sum.x), wm.y - lg2(sum.y),
                               wm.z - lg2(sum.z), wm.w - lg2(sum.w));
        }
        // softor over S (two-pass: max then sum of exp2(P - pm))
        float4 pm = P[0];
#pragma unroll
        for (int s = 1; s < S; ++s) pm = f4max(pm, P[s]);
        float4 ssum = make_float4(0.f, 0.f, 0.f, 0.f);
#pragma unroll
        for (int s = 0; s < S; ++s) ssum = f4add(ssum, f4exp2sub(P[s], pm));
        float4 qv = make_float4(pm.x + lg2(ssum.x), pm.y + lg2(ssum.y),
                                pm.z + lg2(ssum.z), pm.w + lg2(ssum.w));

        int bb = b0 + grp * 4;
        q[(size_t)(c * B + bb + 0) * G + g] = qv.x;
        q[(size_t)(c * B + bb + 1) * G + g] = qv.y;
        q[(size_t)(c * B + bb + 2) * G + g] = qv.z;
        q[(size_t)(c * B + bb + 3) * G + g] = qv.w;
        lmax = fmaxf(lmax, fmaxf(fmaxf(qv.x, qv.y), fmaxf(qv.z, qv.w)));
    }

    float m = lmax;
    for (int off = 32; off; off >>= 1) m = fmaxf(m, __shfl_down(m, off));
    if ((tid & 63) == 0) wmax[tid >> 6] = m;
    __syncthreads();
    if (tid == 0) {
        float mm = fmaxf(fmaxf(wmax[0], wmax[1]), fmaxf(wmax[2], wmax[3]));
        atomicMax(m2k + c, f2key(mm));
    }
}

// grid = 1024 blocks, 2 float4/thread.
__global__ __launch_bounds__(256) void k_merge(const float* __restrict__ src, int step0,
                                               float* __restrict__ R,
                                               const float* __restrict__ q,
                                               const unsigned* __restrict__ m2k,
                                               const unsigned* __restrict__ m3prev,
                                               unsigned* __restrict__ m3out) {
    __shared__ float wmax[4];
    const int tid = threadIdx.x;
    const int c = blockIdx.x >> 6;
    const float ss = step0 ? KF : 1.0f / fmaxf(key2f(*m3prev) * RKF, 1.0f);
    const float qden = 1.0f / fmaxf(key2f(m2k[c]) * RKF, 1.0f);

    float lm = -3.0e38f;
#pragma unroll
    for (int u = 0; u < 2; ++u) {
        int idx = blockIdx.x * 512 + u * 256 + tid;
        int ridx = step0 ? (idx & (BG / 4 - 1)) : idx;
        float4 r4 = ((const float4*)src)[ridx];
        float4 q4 = ((const float4*)q)[idx];
        float rr[4] = {r4.x, r4.y, r4.z, r4.w};
        float qq[4] = {q4.x, q4.y, q4.z, q4.w};
#pragma unroll
        for (int i = 0; i < 4; ++i) {
            float rv = rr[i] * ss;
            float qv = qq[i] * qden;
            float hi = fmaxf(rv, qv), lo = fminf(rv, qv);
            float sv = hi + lg2(1.0f + ex2(lo - hi));
            rr[i] = sv;
            lm = fmaxf(lm, sv);
        }
        ((float4*)R)[idx] = make_float4(rr[0], rr[1], rr[2], rr[3]);
    }

    for (int off = 32; off; off >>= 1) lm = fmaxf(lm, __shfl_down(lm, off));
    if ((tid & 63) == 0) wmax[tid >> 6] = lm;
    __syncthreads();
    if (tid == 0) {
        float mm = fmaxf(fmaxf(wmax[0], wmax[1]), fmaxf(wmax[2], wmax[3]));
        atomicMax(m3out, f2key(mm));
    }
}

__global__ __launch_bounds__(256) void k_scale(float* __restrict__ R,
                                               const unsigned* __restrict__ m3k) {
    float fs = RKF / fmaxf(key2f(*m3k) * RKF, 1.0f);
    int idx = blockIdx.x * 256 + threadIdx.x;
    float4 r = ((float4*)R)[idx];
    r.x *= fs; r.y *= fs; r.z *= fs; r.w *= fs;
    ((float4*)R)[idx] = r;
}

extern "C" void kernel_launch(void* const* d_in, const int* in_sizes, int n_in,
                              void* d_out, int out_size, void* d_ws, size_t ws_size,
                              hipStream_t stream) {
    const float* x = (const float*)d_in[0];   // (B, G) fp32
    const int*   I = (const int*)d_in[1];     // (C, G, S, L) int32
    float* out = (float*)d_out;               // (C, B, G) fp32 (w-units until k_scale)

    float* q = (float*)d_ws;                                               // N floats
    unsigned* mk = (unsigned*)((char*)d_ws + (size_t)N * sizeof(float));   // 64 uints

    hipMemsetAsync(mk, 0, 64 * sizeof(unsigned), stream);

    for (int step = 0; step < STEPS; ++step) {
        int step0 = (step == 0);
        const float* src = step0 ? x : out;
        unsigned* m2k = mk + step * C;
        unsigned* m3out = mk + 48 + step;
        const unsigned* m3prev = mk + 48 + (step ? step - 1 : 0);
        k_clause<<<C * 8 * 8, 256, 0, stream>>>(src, step0, I, q, m2k, m3prev);
        k_merge<<<C * 8 * 8, 256, 0, stream>>>(src, step0, out, q, m2k, m3prev, m3out);
    }
    k_scale<<<N / 4 / 256, 256, 0, stream>>>(out, mk + 48 + STEPS - 1);
}